// Round 1
// baseline (179.234 us; speedup 1.0000x reference)
//
#include <hip/hip_runtime.h>

#define Bsz 8
#define Cn  4
#define Hn  64
#define Wn  2048
#define HW  (Hn*Wn)
#define NPIX (Bsz*HW)

// Gaussian stencil exp(-(dh^2+dw^2)/(2*0.9^2)), center zeroed.
#define G1 0.53940824f   // pd=1
#define G2 0.29096127f   // pd=2
#define G4 0.08465836f   // pd=4
#define G5 0.04566536f   // pd=5

__global__ __launch_bounds__(256) void crf_softmax(const float* __restrict__ Q,
                                                   float* __restrict__ S) {
    int t = blockIdx.x * 256 + threadIdx.x;
    int w = t & (Wn - 1);
    int h = (t >> 11) & (Hn - 1);
    int b = t >> 17;
    size_t base = (size_t)b * Cn * HW + (size_t)h * Wn + w;
    float q0 = Q[base], q1 = Q[base + HW], q2 = Q[base + 2 * HW], q3 = Q[base + 3 * HW];
    float mx = fmaxf(fmaxf(q0, q1), fmaxf(q2, q3));
    float e0 = __expf(q0 - mx), e1 = __expf(q1 - mx);
    float e2 = __expf(q2 - mx), e3 = __expf(q3 - mx);
    float inv = 1.0f / (e0 + e1 + e2 + e3);
    S[base] = e0 * inv;
    S[base + HW] = e1 * inv;
    S[base + 2 * HW] = e2 * inv;
    S[base + 3 * HW] = e3 * inv;
}

__global__ __launch_bounds__(256) void crf_step(const float* __restrict__ S,
                                                const float* __restrict__ unary,
                                                const float* __restrict__ xyz,
                                                const float* __restrict__ mask,
                                                const float* __restrict__ wa,
                                                const float* __restrict__ wsm,
                                                const float* __restrict__ compat,
                                                float* __restrict__ out) {
    int t = blockIdx.x * 256 + threadIdx.x;
    int w = t & (Wn - 1);
    int h = (t >> 11) & (Hn - 1);
    int b = t >> 17;

    size_t pbase = (size_t)b * Cn * HW + (size_t)h * Wn + w;   // channel stride HW
    size_t xbase = (size_t)b * 3 * HW + (size_t)h * Wn + w;
    size_t mbase = (size_t)b * HW + (size_t)h * Wn + w;

    float xc0 = xyz[xbase], xc1 = xyz[xbase + HW], xc2 = xyz[xbase + 2 * HW];
    float mc = mask[mbase];

    const float G[3][5] = {
        {G5, G2, G1, G2, G5},
        {G4, G1, 0.f, G1, G4},
        {G5, G2, G1, G2, G5}};

    float ksm0 = 0.f, ksm1 = 0.f, ksm2 = 0.f, ksm3 = 0.f;
    float app0 = 0.f, app1 = 0.f, app2 = 0.f, app3 = 0.f;

#pragma unroll
    for (int dh = -1; dh <= 1; ++dh) {
        int hh = h + dh;
        if (hh < 0 || hh >= Hn) continue;
#pragma unroll
        for (int dw = -2; dw <= 2; ++dw) {
            if (dh == 0 && dw == 0) continue;
            int ww = w + dw;
            if (ww < 0 || ww >= Wn) continue;
            int off = dh * Wn + dw;
            float g = G[dh + 1][dw + 2];
            float s0 = S[pbase + off];
            float s1 = S[pbase + off + HW];
            float s2 = S[pbase + off + 2 * HW];
            float s3 = S[pbase + off + 3 * HW];
            ksm0 += g * s0; ksm1 += g * s1; ksm2 += g * s2; ksm3 += g * s3;
            float dx = xyz[xbase + off] - xc0;
            float dy = xyz[xbase + off + HW] - xc1;
            float dz = xyz[xbase + off + 2 * HW] - xc2;
            float d2 = dx * dx + dy * dy + dz * dz;
            float beta = __expf(-2222.2222f * d2);     // 1/(2*0.015^2)
            float bm = beta * mask[mbase + off];
            app0 += bm * s0; app1 += bm * s1; app2 += bm * s2; app3 += bm * s3;
        }
    }

    // weighted_k[c] = wsm[c]*ksm[c] + wa[c]*(app[c]*mc)*ksm[c]
    float wk0 = ksm0 * (wsm[0] + wa[0] * (app0 * mc));
    float wk1 = ksm1 * (wsm[1] + wa[1] * (app1 * mc));
    float wk2 = ksm2 * (wsm[2] + wa[2] * (app2 * mc));
    float wk3 = ksm3 * (wsm[3] + wa[3] * (app3 * mc));

#pragma unroll
    for (int o = 0; o < Cn; ++o) {
        float pw = compat[o * 4 + 0] * wk0 + compat[o * 4 + 1] * wk1 +
                   compat[o * 4 + 2] * wk2 + compat[o * 4 + 3] * wk3;
        out[pbase + (size_t)o * HW] = unary[pbase + (size_t)o * HW] - pw;
    }
}

extern "C" void kernel_launch(void* const* d_in, const int* in_sizes, int n_in,
                              void* d_out, int out_size, void* d_ws, size_t ws_size,
                              hipStream_t stream) {
    const float* unary  = (const float*)d_in[0];
    const float* xyz    = (const float*)d_in[1];
    const float* mask   = (const float*)d_in[2];
    const float* wa     = (const float*)d_in[3];
    const float* wsm    = (const float*)d_in[4];
    const float* compat = (const float*)d_in[5];
    float* outp = (float*)d_out;

    float* S  = (float*)d_ws;                    // softmaxed Q, 16 MiB
    float* Qb = S + (size_t)Bsz * Cn * HW;       // iterated Q,  16 MiB

    dim3 grid(NPIX / 256), blk(256);

    // iter 0
    crf_softmax<<<grid, blk, 0, stream>>>(unary, S);
    crf_step<<<grid, blk, 0, stream>>>(S, unary, xyz, mask, wa, wsm, compat, Qb);
    // iter 1
    crf_softmax<<<grid, blk, 0, stream>>>(Qb, S);
    crf_step<<<grid, blk, 0, stream>>>(S, unary, xyz, mask, wa, wsm, compat, Qb);
    // iter 2
    crf_softmax<<<grid, blk, 0, stream>>>(Qb, S);
    crf_step<<<grid, blk, 0, stream>>>(S, unary, xyz, mask, wa, wsm, compat, outp);
}

// Round 2
// 133.684 us; speedup vs baseline: 1.3407x; 1.3407x over previous
//
#include <hip/hip_runtime.h>

#define Bsz 8
#define Cn  4
#define Hn  64
#define Wn  2048
#define HW  (Hn*Wn)

#define TW 64
#define TH 4
#define HALO_W (TW+4)        // 68
#define HALO_H (TH+2)        // 6
#define NHALO (HALO_W*HALO_H) // 408

// Gaussian stencil exp(-(dh^2+dw^2)/(2*0.9^2)), center zeroed.
#define G1 0.53940824f   // pd=1
#define G2 0.29096127f   // pd=2
#define G4 0.08465836f   // pd=4
#define G5 0.04566536f   // pd=5

__global__ __launch_bounds__(256) void crf_iter(const float* __restrict__ Qin,
                                                const float* __restrict__ unary,
                                                const float* __restrict__ xyz,
                                                const float* __restrict__ mask,
                                                const float* __restrict__ wa,
                                                const float* __restrict__ wsm,
                                                const float* __restrict__ compat,
                                                float* __restrict__ Qout) {
    __shared__ float4 Sl[NHALO];   // softmax(Q) halo, c-contiguous
    __shared__ float4 Xl[NHALO];   // xyz in .xyz, mask in .w

    const int tid = threadIdx.x;
    const int w0 = blockIdx.x * TW;
    const int h0 = blockIdx.y * TH;
    const int b  = blockIdx.z;

    const size_t qbase = (size_t)b * Cn * HW;
    const size_t xbase = (size_t)b * 3 * HW;
    const size_t mbase = (size_t)b * HW;

    // ---- stage softmax(Q) + (xyz,mask) for the halo tile into LDS ----
    for (int i = tid; i < NHALO; i += 256) {
        int hr = i / HALO_W;
        int hw = i - hr * HALO_W;
        int gh = h0 + hr - 1;
        int gw = w0 + hw - 2;
        float4 s  = make_float4(0.f, 0.f, 0.f, 0.f);
        float4 xm = make_float4(0.f, 0.f, 0.f, 0.f);
        if (gh >= 0 && gh < Hn && gw >= 0 && gw < Wn) {
            size_t p = (size_t)gh * Wn + gw;
            float q0 = Qin[qbase + p];
            float q1 = Qin[qbase + p + HW];
            float q2 = Qin[qbase + p + 2 * HW];
            float q3 = Qin[qbase + p + 3 * HW];
            float mx = fmaxf(fmaxf(q0, q1), fmaxf(q2, q3));
            float e0 = __expf(q0 - mx), e1 = __expf(q1 - mx);
            float e2 = __expf(q2 - mx), e3 = __expf(q3 - mx);
            float inv = 1.0f / (e0 + e1 + e2 + e3);
            s = make_float4(e0 * inv, e1 * inv, e2 * inv, e3 * inv);
            xm = make_float4(xyz[xbase + p], xyz[xbase + p + HW],
                             xyz[xbase + p + 2 * HW], mask[mbase + p]);
        }
        Sl[i] = s;
        Xl[i] = xm;
    }
    __syncthreads();

    // ---- fused step for this thread's pixel ----
    const int lw = (tid & 63) + 2;
    const int lr = (tid >> 6) + 1;
    const int gw = w0 + (tid & 63);
    const int gh = h0 + (tid >> 6);
    const size_t p = (size_t)gh * Wn + gw;

    const float4 xc = Xl[lr * HALO_W + lw];
    const float mc = xc.w;

    const float Gt[3][5] = {
        {G5, G2, G1, G2, G5},
        {G4, G1, 0.f, G1, G4},
        {G5, G2, G1, G2, G5}};

    float ksm0 = 0.f, ksm1 = 0.f, ksm2 = 0.f, ksm3 = 0.f;
    float app0 = 0.f, app1 = 0.f, app2 = 0.f, app3 = 0.f;

#pragma unroll
    for (int dh = -1; dh <= 1; ++dh) {
#pragma unroll
        for (int dw = -2; dw <= 2; ++dw) {
            if (dh == 0 && dw == 0) continue;
            const int li = (lr + dh) * HALO_W + (lw + dw);
            float4 s  = Sl[li];
            float4 xm = Xl[li];
            const float g = Gt[dh + 1][dw + 2];
            ksm0 += g * s.x; ksm1 += g * s.y; ksm2 += g * s.z; ksm3 += g * s.w;
            float dx = xm.x - xc.x;
            float dy = xm.y - xc.y;
            float dz = xm.z - xc.z;
            float beta = __expf(-2222.2222f * (dx * dx + dy * dy + dz * dz));
            float bm = beta * xm.w;
            app0 += bm * s.x; app1 += bm * s.y; app2 += bm * s.z; app3 += bm * s.w;
        }
    }

    // weighted_k[c] = wsm[c]*ksm[c] + wa[c]*(app[c]*mc)*ksm[c]
    float wk0 = ksm0 * (wsm[0] + wa[0] * (app0 * mc));
    float wk1 = ksm1 * (wsm[1] + wa[1] * (app1 * mc));
    float wk2 = ksm2 * (wsm[2] + wa[2] * (app2 * mc));
    float wk3 = ksm3 * (wsm[3] + wa[3] * (app3 * mc));

#pragma unroll
    for (int o = 0; o < Cn; ++o) {
        float pw = compat[o * 4 + 0] * wk0 + compat[o * 4 + 1] * wk1 +
                   compat[o * 4 + 2] * wk2 + compat[o * 4 + 3] * wk3;
        Qout[qbase + p + (size_t)o * HW] = unary[qbase + p + (size_t)o * HW] - pw;
    }
}

extern "C" void kernel_launch(void* const* d_in, const int* in_sizes, int n_in,
                              void* d_out, int out_size, void* d_ws, size_t ws_size,
                              hipStream_t stream) {
    const float* unary  = (const float*)d_in[0];
    const float* xyz    = (const float*)d_in[1];
    const float* mask   = (const float*)d_in[2];
    const float* wa     = (const float*)d_in[3];
    const float* wsm    = (const float*)d_in[4];
    const float* compat = (const float*)d_in[5];
    float* outp = (float*)d_out;

    float* Q1 = (float*)d_ws;                    // 16 MiB
    float* Q2 = Q1 + (size_t)Bsz * Cn * HW;      // 16 MiB

    dim3 grid(Wn / TW, Hn / TH, Bsz), blk(256);

    crf_iter<<<grid, blk, 0, stream>>>(unary, unary, xyz, mask, wa, wsm, compat, Q1);
    crf_iter<<<grid, blk, 0, stream>>>(Q1,    unary, xyz, mask, wa, wsm, compat, Q2);
    crf_iter<<<grid, blk, 0, stream>>>(Q2,    unary, xyz, mask, wa, wsm, compat, outp);
}